// Round 9
// baseline (235.826 us; speedup 1.0000x reference)
//
#include <hip/hip_runtime.h>
#include <cmath>

#define C_DIM 2048
#define B_DIM 16
#define H_DIM 16
#define HS_DIM 128
#define T_DIM 4096
#define ATT_SCALE 0.08838834764831845f  // 1/sqrt(128)
#define TCHUNK 512
#define NCHUNK (T_DIM / TCHUNK)         // 8 blocks per (b,h)

typedef float fx4 __attribute__((ext_vector_type(4)));

__device__ __forceinline__ float4 nt_load4(const float* p) {
  const fx4 r = __builtin_nontemporal_load(reinterpret_cast<const fx4*>(p));
  return make_float4(r.x, r.y, r.z, r.w);
}

// ---------------------------------------------------------------------------
// Kernel 1 & 4: O[16, 2048] = X[16, 2048] @ W[2048, 2048]^T
// W rows streamed with nontemporal loads (read exactly once).
// ---------------------------------------------------------------------------
__global__ __launch_bounds__(256) void gemv16_kernel(
    const float* __restrict__ X, const float* __restrict__ W,
    float* __restrict__ O) {
  const int lane = threadIdx.x & 63;
  const int wave = threadIdx.x >> 6;            // 0..3
  const int n = blockIdx.x * 4 + wave;          // output column
  const float* wrow = W + (size_t)n * C_DIM;

  float acc[B_DIM];
#pragma unroll
  for (int m = 0; m < B_DIM; ++m) acc[m] = 0.f;

#pragma unroll
  for (int i = 0; i < C_DIM / 256; ++i) {
    const int j = (i * 64 + lane) * 4;
    const float4 w4 = nt_load4(wrow + j);
#pragma unroll
    for (int m = 0; m < B_DIM; ++m) {
      const float4 x4 = *reinterpret_cast<const float4*>(X + m * C_DIM + j);
      acc[m] += w4.x * x4.x + w4.y * x4.y + w4.z * x4.z + w4.w * x4.w;
    }
  }

#pragma unroll
  for (int m = 0; m < B_DIM; ++m) {
#pragma unroll
    for (int mask = 32; mask >= 1; mask >>= 1)
      acc[m] += __shfl_xor(acc[m], mask, 64);
  }
  if (lane == 0) {
#pragma unroll
    for (int m = 0; m < B_DIM; ++m) O[(size_t)m * C_DIM + n] = acc[m];
  }
}

// ---------------------------------------------------------------------------
// Kernel 2: attention partials. Grid = B*H*NCHUNK = 2048 blocks x 256 thr.
// Each (wave,half) unit owns 64 rows; processes 8 rows per iteration with all
// 16 k/v float4 loads (nt) issued up front, then one group-rescale online
// softmax update. 8 units merge via LDS into one block partial.
// ---------------------------------------------------------------------------
__global__ __launch_bounds__(256, 4) void attn_partial_kernel(
    const float* __restrict__ q, const float* __restrict__ k,
    const float* __restrict__ v, float* __restrict__ pm,
    float* __restrict__ pl, float* __restrict__ py) {
  const int blk = blockIdx.x;                   // bh*NCHUNK + chunk
  const int bh = blk >> 3;
  const int chunk = blk & 7;
  const int lane = threadIdx.x & 63;
  const int wave = threadIdx.x >> 6;            // 0..3
  const int half = lane >> 5;
  const int dl = lane & 31;                     // dim-quad index
  const int unit = wave * 2 + half;             // 0..7

  const float* kp = k + (size_t)bh * T_DIM * HS_DIM;
  const float* vp = v + (size_t)bh * T_DIM * HS_DIM;
  const float4 qv = reinterpret_cast<const float4*>(q + (size_t)bh * HS_DIM)[dl];

  float m = -INFINITY, l = 0.f;
  float y0 = 0.f, y1 = 0.f, y2 = 0.f, y3 = 0.f;
  const int tbase = chunk * TCHUNK + unit;

  for (int ti = 0; ti < TCHUNK / 64; ++ti) {    // 8 iters, 8 rows/unit/iter
    const size_t t = tbase + (size_t)ti * 64;
    float4 kr[8], vr[8];
#pragma unroll
    for (int r = 0; r < 8; ++r)
      kr[r] = nt_load4(kp + (t + r * 8) * HS_DIM + dl * 4);
#pragma unroll
    for (int r = 0; r < 8; ++r)
      vr[r] = nt_load4(vp + (t + r * 8) * HS_DIM + dl * 4);

    float s[8];
#pragma unroll
    for (int r = 0; r < 8; ++r)
      s[r] = kr[r].x * qv.x + kr[r].y * qv.y + kr[r].z * qv.z + kr[r].w * qv.w;
#pragma unroll
    for (int mask = 16; mask >= 1; mask >>= 1) {
#pragma unroll
      for (int r = 0; r < 8; ++r) s[r] += __shfl_xor(s[r], mask, 64);
    }
    float smax = -INFINITY;
#pragma unroll
    for (int r = 0; r < 8; ++r) { s[r] *= ATT_SCALE; smax = fmaxf(smax, s[r]); }

    const float mn = fmaxf(m, smax);
    const float c = __expf(m - mn);             // exp(-inf)=0 on first iter
    float e[8];
    float esum = 0.f;
#pragma unroll
    for (int r = 0; r < 8; ++r) { e[r] = __expf(s[r] - mn); esum += e[r]; }
    l = fmaf(l, c, esum);
    y0 *= c; y1 *= c; y2 *= c; y3 *= c;
#pragma unroll
    for (int r = 0; r < 8; ++r) {
      y0 = fmaf(e[r], vr[r].x, y0);
      y1 = fmaf(e[r], vr[r].y, y1);
      y2 = fmaf(e[r], vr[r].z, y2);
      y3 = fmaf(e[r], vr[r].w, y3);
    }
    m = mn;
  }

  __shared__ float lm[8];
  __shared__ float ll[8];
  __shared__ float ly[8 * HS_DIM];
  reinterpret_cast<float4*>(ly)[unit * 32 + dl] = make_float4(y0, y1, y2, y3);
  if (dl == 0) { lm[unit] = m; ll[unit] = l; }
  __syncthreads();

  const int tid = threadIdx.x;
  if (tid < HS_DIM) {
    float gm = lm[0];
#pragma unroll
    for (int u = 1; u < 8; ++u) gm = fmaxf(gm, lm[u]);
    float L = 0.f, yd = 0.f;
#pragma unroll
    for (int u = 0; u < 8; ++u) {
      const float e = __expf(lm[u] - gm);
      L = fmaf(e, ll[u], L);
      yd = fmaf(e, ly[u * HS_DIM + tid], yd);
    }
    py[(size_t)blk * HS_DIM + tid] = yd;
    if (tid == 0) { pm[blk] = gm; pl[blk] = L; }
  }
}

// ---------------------------------------------------------------------------
// Kernel 3: merge NCHUNK partials per (b,h). Grid 256, 128 threads.
// ---------------------------------------------------------------------------
__global__ __launch_bounds__(128) void attn_combine_kernel(
    const float* __restrict__ pm, const float* __restrict__ pl,
    const float* __restrict__ py, float* __restrict__ y) {
  const int bh = blockIdx.x;
  const int d = threadIdx.x;
  float gm = -INFINITY;
#pragma unroll
  for (int c = 0; c < NCHUNK; ++c) gm = fmaxf(gm, pm[bh * NCHUNK + c]);
  float L = 0.f, yd = 0.f;
#pragma unroll
  for (int c = 0; c < NCHUNK; ++c) {
    const float e = __expf(pm[bh * NCHUNK + c] - gm);
    L = fmaf(e, pl[bh * NCHUNK + c], L);
    yd = fmaf(e, py[(size_t)(bh * NCHUNK + c) * HS_DIM + d], yd);
  }
  y[(size_t)bh * HS_DIM + d] = yd / L;
}

extern "C" void kernel_launch(void* const* d_in, const int* in_sizes, int n_in,
                              void* d_out, int out_size, void* d_ws, size_t ws_size,
                              hipStream_t stream) {
  const float* x  = (const float*)d_in[0];   // [16, 1, 2048]
  const float* k  = (const float*)d_in[1];   // [16, 16, 4096, 128]
  const float* v  = (const float*)d_in[2];   // [16, 16, 4096, 128]
  const float* Wq = (const float*)d_in[3];   // [2048, 2048]
  const float* Wp = (const float*)d_in[4];   // [2048, 2048]
  float* out = (float*)d_out;                // [16, 1, 2048]

  float* ws   = (float*)d_ws;
  float* q_ws = ws;                          // [16, 2048]
  float* y_ws = ws + B_DIM * C_DIM;          // [16, 2048]
  float* pm   = y_ws + B_DIM * C_DIM;        // [2048]
  float* pl   = pm + B_DIM * H_DIM * NCHUNK; // [2048]
  float* py   = pl + B_DIM * H_DIM * NCHUNK; // [2048 * 128]

  hipLaunchKernelGGL(gemv16_kernel, dim3(C_DIM / 4), dim3(256), 0, stream,
                     x, Wq, q_ws);
  hipLaunchKernelGGL(attn_partial_kernel, dim3(B_DIM * H_DIM * NCHUNK), dim3(256), 0, stream,
                     q_ws, k, v, pm, pl, py);
  hipLaunchKernelGGL(attn_combine_kernel, dim3(B_DIM * H_DIM), dim3(128), 0, stream,
                     pm, pl, py, y_ws);
  hipLaunchKernelGGL(gemv16_kernel, dim3(C_DIM / 4), dim3(256), 0, stream,
                     y_ws, Wp, out);
}

// Round 10
// 226.032 us; speedup vs baseline: 1.0433x; 1.0433x over previous
//
#include <hip/hip_runtime.h>
#include <cmath>

#define C_DIM 2048
#define B_DIM 16
#define H_DIM 16
#define HS_DIM 128
#define T_DIM 4096
#define ATT_SCALE 0.08838834764831845f  // 1/sqrt(128)
#define TCHUNK 512
#define NCHUNK (T_DIM / TCHUNK)         // 8 blocks per (b,h)

typedef float fx4 __attribute__((ext_vector_type(4)));

__device__ __forceinline__ float4 nt_load4(const float* p) {
  const fx4 r = __builtin_nontemporal_load(reinterpret_cast<const fx4*>(p));
  return make_float4(r.x, r.y, r.z, r.w);
}

// ---------------------------------------------------------------------------
// Kernel 1 & 4: O[16, 2048] = X[16, 2048] @ W[2048, 2048]^T
// W rows streamed with nontemporal loads (read exactly once).
// ---------------------------------------------------------------------------
__global__ __launch_bounds__(256) void gemv16_kernel(
    const float* __restrict__ X, const float* __restrict__ W,
    float* __restrict__ O) {
  const int lane = threadIdx.x & 63;
  const int wave = threadIdx.x >> 6;            // 0..3
  const int n = blockIdx.x * 4 + wave;          // output column
  const float* wrow = W + (size_t)n * C_DIM;

  float acc[B_DIM];
#pragma unroll
  for (int m = 0; m < B_DIM; ++m) acc[m] = 0.f;

#pragma unroll
  for (int i = 0; i < C_DIM / 256; ++i) {
    const int j = (i * 64 + lane) * 4;
    const float4 w4 = nt_load4(wrow + j);
#pragma unroll
    for (int m = 0; m < B_DIM; ++m) {
      const float4 x4 = *reinterpret_cast<const float4*>(X + m * C_DIM + j);
      acc[m] += w4.x * x4.x + w4.y * x4.y + w4.z * x4.z + w4.w * x4.w;
    }
  }

#pragma unroll
  for (int m = 0; m < B_DIM; ++m) {
#pragma unroll
    for (int mask = 32; mask >= 1; mask >>= 1)
      acc[m] += __shfl_xor(acc[m], mask, 64);
  }
  if (lane == 0) {
#pragma unroll
    for (int m = 0; m < B_DIM; ++m) O[(size_t)m * C_DIM + n] = acc[m];
  }
}

// ---------------------------------------------------------------------------
// Kernel 2: attention partials. Grid = B*H*NCHUNK = 2048 blocks x 256 thr.
// Each (wave,half) unit owns 64 rows; processes 4 rows per iteration with all
// 8 k/v float4 loads (nt) issued up front, then a single group-rescale online
// softmax update. 8 units merge via LDS into one block partial.
// ---------------------------------------------------------------------------
__global__ __launch_bounds__(256, 4) void attn_partial_kernel(
    const float* __restrict__ q, const float* __restrict__ k,
    const float* __restrict__ v, float* __restrict__ pm,
    float* __restrict__ pl, float* __restrict__ py) {
  const int blk = blockIdx.x;                   // bh*NCHUNK + chunk
  const int bh = blk >> 3;
  const int chunk = blk & 7;
  const int lane = threadIdx.x & 63;
  const int wave = threadIdx.x >> 6;            // 0..3
  const int half = lane >> 5;
  const int dl = lane & 31;                     // dim-quad index
  const int unit = wave * 2 + half;             // 0..7

  const float* kp = k + (size_t)bh * T_DIM * HS_DIM;
  const float* vp = v + (size_t)bh * T_DIM * HS_DIM;
  const float4 qv = reinterpret_cast<const float4*>(q + (size_t)bh * HS_DIM)[dl];

  float m = -INFINITY, l = 0.f;
  float y0 = 0.f, y1 = 0.f, y2 = 0.f, y3 = 0.f;
  const int tbase = chunk * TCHUNK + unit;

#pragma unroll 2
  for (int ti = 0; ti < TCHUNK / 32; ++ti) {    // 16 iters, 4 rows/unit/iter
    const size_t t = tbase + (size_t)ti * 32;
    const float4 k0 = nt_load4(kp + (t +  0) * HS_DIM + dl * 4);
    const float4 k1 = nt_load4(kp + (t +  8) * HS_DIM + dl * 4);
    const float4 k2 = nt_load4(kp + (t + 16) * HS_DIM + dl * 4);
    const float4 k3 = nt_load4(kp + (t + 24) * HS_DIM + dl * 4);
    const float4 v0 = nt_load4(vp + (t +  0) * HS_DIM + dl * 4);
    const float4 v1 = nt_load4(vp + (t +  8) * HS_DIM + dl * 4);
    const float4 v2 = nt_load4(vp + (t + 16) * HS_DIM + dl * 4);
    const float4 v3 = nt_load4(vp + (t + 24) * HS_DIM + dl * 4);

    float s0 = k0.x * qv.x + k0.y * qv.y + k0.z * qv.z + k0.w * qv.w;
    float s1 = k1.x * qv.x + k1.y * qv.y + k1.z * qv.z + k1.w * qv.w;
    float s2 = k2.x * qv.x + k2.y * qv.y + k2.z * qv.z + k2.w * qv.w;
    float s3 = k3.x * qv.x + k3.y * qv.y + k3.z * qv.z + k3.w * qv.w;
#pragma unroll
    for (int mask = 16; mask >= 1; mask >>= 1) {
      s0 += __shfl_xor(s0, mask, 64);
      s1 += __shfl_xor(s1, mask, 64);
      s2 += __shfl_xor(s2, mask, 64);
      s3 += __shfl_xor(s3, mask, 64);
    }
    s0 *= ATT_SCALE; s1 *= ATT_SCALE; s2 *= ATT_SCALE; s3 *= ATT_SCALE;

    const float smax = fmaxf(fmaxf(s0, s1), fmaxf(s2, s3));
    const float mn = fmaxf(m, smax);
    const float c = __expf(m - mn);             // exp(-inf)=0 on first iter
    const float e0 = __expf(s0 - mn);
    const float e1 = __expf(s1 - mn);
    const float e2 = __expf(s2 - mn);
    const float e3 = __expf(s3 - mn);
    l = fmaf(l, c, e0 + e1 + e2 + e3);
    y0 = fmaf(e3, v3.x, fmaf(e2, v2.x, fmaf(e1, v1.x, fmaf(e0, v0.x, y0 * c))));
    y1 = fmaf(e3, v3.y, fmaf(e2, v2.y, fmaf(e1, v1.y, fmaf(e0, v0.y, y1 * c))));
    y2 = fmaf(e3, v3.z, fmaf(e2, v2.z, fmaf(e1, v1.z, fmaf(e0, v0.z, y2 * c))));
    y3 = fmaf(e3, v3.w, fmaf(e2, v2.w, fmaf(e1, v1.w, fmaf(e0, v0.w, y3 * c))));
    m = mn;
  }

  __shared__ float lm[8];
  __shared__ float ll[8];
  __shared__ float ly[8 * HS_DIM];
  reinterpret_cast<float4*>(ly)[unit * 32 + dl] = make_float4(y0, y1, y2, y3);
  if (dl == 0) { lm[unit] = m; ll[unit] = l; }
  __syncthreads();

  const int tid = threadIdx.x;
  if (tid < HS_DIM) {
    float gm = lm[0];
#pragma unroll
    for (int u = 1; u < 8; ++u) gm = fmaxf(gm, lm[u]);
    float L = 0.f, yd = 0.f;
#pragma unroll
    for (int u = 0; u < 8; ++u) {
      const float e = __expf(lm[u] - gm);
      L = fmaf(e, ll[u], L);
      yd = fmaf(e, ly[u * HS_DIM + tid], yd);
    }
    py[(size_t)blk * HS_DIM + tid] = yd;
    if (tid == 0) { pm[blk] = gm; pl[blk] = L; }
  }
}

// ---------------------------------------------------------------------------
// Kernel 3: merge NCHUNK partials per (b,h). Grid 256, 128 threads.
// ---------------------------------------------------------------------------
__global__ __launch_bounds__(128) void attn_combine_kernel(
    const float* __restrict__ pm, const float* __restrict__ pl,
    const float* __restrict__ py, float* __restrict__ y) {
  const int bh = blockIdx.x;
  const int d = threadIdx.x;
  float gm = -INFINITY;
#pragma unroll
  for (int c = 0; c < NCHUNK; ++c) gm = fmaxf(gm, pm[bh * NCHUNK + c]);
  float L = 0.f, yd = 0.f;
#pragma unroll
  for (int c = 0; c < NCHUNK; ++c) {
    const float e = __expf(pm[bh * NCHUNK + c] - gm);
    L = fmaf(e, pl[bh * NCHUNK + c], L);
    yd = fmaf(e, py[(size_t)(bh * NCHUNK + c) * HS_DIM + d], yd);
  }
  y[(size_t)bh * HS_DIM + d] = yd / L;
}

extern "C" void kernel_launch(void* const* d_in, const int* in_sizes, int n_in,
                              void* d_out, int out_size, void* d_ws, size_t ws_size,
                              hipStream_t stream) {
  const float* x  = (const float*)d_in[0];   // [16, 1, 2048]
  const float* k  = (const float*)d_in[1];   // [16, 16, 4096, 128]
  const float* v  = (const float*)d_in[2];   // [16, 16, 4096, 128]
  const float* Wq = (const float*)d_in[3];   // [2048, 2048]
  const float* Wp = (const float*)d_in[4];   // [2048, 2048]
  float* out = (float*)d_out;                // [16, 1, 2048]

  float* ws   = (float*)d_ws;
  float* q_ws = ws;                          // [16, 2048]
  float* y_ws = ws + B_DIM * C_DIM;          // [16, 2048]
  float* pm   = y_ws + B_DIM * C_DIM;        // [2048]
  float* pl   = pm + B_DIM * H_DIM * NCHUNK; // [2048]
  float* py   = pl + B_DIM * H_DIM * NCHUNK; // [2048 * 128]

  hipLaunchKernelGGL(gemv16_kernel, dim3(C_DIM / 4), dim3(256), 0, stream,
                     x, Wq, q_ws);
  hipLaunchKernelGGL(attn_partial_kernel, dim3(B_DIM * H_DIM * NCHUNK), dim3(256), 0, stream,
                     q_ws, k, v, pm, pl, py);
  hipLaunchKernelGGL(attn_combine_kernel, dim3(B_DIM * H_DIM), dim3(128), 0, stream,
                     pm, pl, py, y_ws);
  hipLaunchKernelGGL(gemv16_kernel, dim3(C_DIM / 4), dim3(256), 0, stream,
                     y_ws, Wp, out);
}